// Round 4
// baseline (12786.907 us; speedup 1.0000x reference)
//
#include <hip/hip_runtime.h>
#include <cstdint>
#include <math.h>

#define DIMX 320
#define NH 4
#define DHX 80
#define GX 19357
#define NBX 350
#define BX 2
#define NEX 160000
#define E2X (NEX + GX)      // 179357 edges incl. self loops
#define BGX (BX * GX)       // 38714 rows
#define FFX 1280
#define BHX (BX * NH)       // 8

// ---------- helpers ----------
__device__ __forceinline__ unsigned f2o(float f) {
  unsigned u = __float_as_uint(f);
  return (u & 0x80000000u) ? ~u : (u | 0x80000000u);
}
__device__ __forceinline__ float o2f(unsigned u) {
  return __uint_as_float((u & 0x80000000u) ? (u & 0x7FFFFFFFu) : ~u);
}
__device__ __forceinline__ float wave_sum(float v) {
  #pragma unroll
  for (int o = 32; o; o >>= 1) v += __shfl_xor(v, o, 64);
  return v;
}
__device__ __forceinline__ float wave_max(float v) {
  #pragma unroll
  for (int o = 32; o; o >>= 1) v = fmaxf(v, __shfl_xor(v, o, 64));
  return v;
}
__device__ __forceinline__ float grp16_sum(float v) {
  #pragma unroll
  for (int o = 8; o; o >>= 1) v += __shfl_xor(v, o, 64);
  return v;
}

// ---------- generic fp32 GEMM: C = [C +] alpha*(A @ B[^T]) [*rowscale] [+ bias] ----------
// block 256 threads, tile 128(M) x 64(N), K-tile 16, 8x4 acc per thread.
// z offsets: za=zA0+bz (A side), zb=zB0+bz (B side), zc=zC0+bz (C + rowscale side).
#define GTM 128
#define GTN 64
#define GTK 16
template<bool ADD_C, bool HAS_BIAS, bool TRANS_B, bool ROW_SCALE>
__global__ __launch_bounds__(256)
void gemm_kernel(const float* __restrict__ A, int lda, int Adiv, size_t Ab_hi, size_t Ab_lo, int zA0,
                 const float* __restrict__ Bm, int ldb, size_t Bb, int zB0,
                 const float* __restrict__ bias,
                 const float* __restrict__ rs, size_t rs_stride,
                 float* __restrict__ C, int ldc, int Cdiv, size_t Cb_hi, size_t Cb_lo, int zC0,
                 int M, int N, int K, float alpha)
{
  int bz = blockIdx.z;
  int za = zA0 + bz, zb = zB0 + bz, zc = zC0 + bz;
  A  += (size_t)(za / Adiv) * Ab_hi + (size_t)(za % Adiv) * Ab_lo;
  Bm += (size_t)zb * Bb;
  C  += (size_t)(zc / Cdiv) * Cb_hi + (size_t)(zc % Cdiv) * Cb_lo;
  const float* rsz = ROW_SCALE ? (rs + (size_t)zc * rs_stride) : nullptr;

  __shared__ float As[GTK][GTM + 4];
  __shared__ float Bs[GTK][GTN + 4];
  int tid = threadIdx.x;
  int ty = tid >> 4, tx = tid & 15;
  int row0 = blockIdx.y * GTM, col0 = blockIdx.x * GTN;
  float acc[8][4] = {};

  for (int k0 = 0; k0 < K; k0 += GTK) {
    #pragma unroll
    for (int i = 0; i < 8; ++i) {
      int m = (tid >> 4) + i * 16, k = tid & 15;
      int gm = row0 + m, gk = k0 + k;
      As[k][m] = (gm < M && gk < K) ? A[(size_t)gm * lda + gk] : 0.f;
    }
    if (!TRANS_B) {
      #pragma unroll
      for (int i = 0; i < 4; ++i) {
        int k = (tid >> 6) + i * 4, n = tid & 63;
        int gk = k0 + k, gn = col0 + n;
        Bs[k][n] = (gk < K && gn < N) ? Bm[(size_t)gk * ldb + gn] : 0.f;
      }
    } else {
      #pragma unroll
      for (int i = 0; i < 4; ++i) {
        int k = tid & 15, n = (tid >> 4) + i * 16;
        int gk = k0 + k, gn = col0 + n;
        Bs[k][n] = (gk < K && gn < N) ? Bm[(size_t)gn * ldb + gk] : 0.f;
      }
    }
    __syncthreads();
    #pragma unroll
    for (int k = 0; k < GTK; ++k) {
      float4 a0 = *(const float4*)&As[k][ty * 8];
      float4 a1 = *(const float4*)&As[k][ty * 8 + 4];
      float4 b0 = *(const float4*)&Bs[k][tx * 4];
      float a[8] = {a0.x, a0.y, a0.z, a0.w, a1.x, a1.y, a1.z, a1.w};
      float bb[4] = {b0.x, b0.y, b0.z, b0.w};
      #pragma unroll
      for (int i = 0; i < 8; ++i)
        #pragma unroll
        for (int j = 0; j < 4; ++j) acc[i][j] += a[i] * bb[j];
    }
    __syncthreads();
  }

  #pragma unroll
  for (int i = 0; i < 8; ++i) {
    int gm = row0 + ty * 8 + i;
    if (gm >= M) continue;
    float scale = ROW_SCALE ? rsz[gm] : 1.f;
    #pragma unroll
    for (int j = 0; j < 4; ++j) {
      int gn = col0 + tx * 4 + j;
      if (gn >= N) continue;
      float v = alpha * acc[i][j];
      if (ROW_SCALE) v *= scale;
      if (HAS_BIAS) v += bias[gn];
      if (ADD_C) v += C[(size_t)gm * ldc + gn];
      C[(size_t)gm * ldc + gn] = v;
    }
  }
}

// ---------- small kernels ----------
__global__ void fill_u32_kernel(unsigned* __restrict__ p, unsigned v, int n) {
  int i = blockIdx.x * blockDim.x + threadIdx.x;
  if (i < n) p[i] = v;
}

__global__ void ctx_kernel(const int* __restrict__ idx, const float* __restrict__ ae,
                           const float* __restrict__ w, const float* __restrict__ b,
                           float* __restrict__ ctx) {
  int bb = blockIdx.y;
  int n = blockIdx.x * 64 + threadIdx.x;
  if (n >= DIMX) return;
  const float* a = ae + (size_t)idx[bb] * DIMX;
  float s = b[n];
  for (int k = 0; k < DIMX; ++k) s += a[k] * w[(size_t)k * DIMX + n];
  ctx[bb * DIMX + n] = s;
}

__global__ void pre_kernel(const float* __restrict__ x_expr, const float* __restrict__ gene,
                           const float* __restrict__ ctx, float* __restrict__ pre) {
  int i = blockIdx.x * blockDim.x + threadIdx.x;
  if (i >= BGX * DIMX) return;
  int d = i % DIMX;
  int bg = i / DIMX;
  int b = bg / GX, g = bg % GX;
  float xv = x_expr[bg];
  int ii = (d < DIMX / 2) ? (d + 1) : (d - DIMX / 2 + 1);
  float theta = exp2f(6.643856189774724f * ((float)ii * (1.0f / 160.0f)));
  float ang = xv * theta;
  float r = (d < DIMX / 2) ? sinf(ang) : cosf(ang);
  pre[i] = r + gene[(size_t)g * DIMX + d] + ctx[b * DIMX + d];
}

__global__ void bias_init_kernel(float* __restrict__ o, const float* __restrict__ b) {
  int i = blockIdx.x * blockDim.x + threadIdx.x;
  if (i >= BGX * DIMX) return;
  o[i] = b[i % DIMX];
}

// ---------- GAT ----------
__global__ void gat_logit_kernel(const float* __restrict__ xl, const float* __restrict__ xr,
                                 const float* __restrict__ att, const int* __restrict__ ei,
                                 float* __restrict__ logit, unsigned* __restrict__ lmax) {
  int widx = (blockIdx.x * blockDim.x + threadIdx.x) >> 6;
  int lane = threadIdx.x & 63;
  if (widx >= BX * E2X) return;
  int b = widx / E2X, e = widx % E2X;
  int s, t;
  if (e < NEX) { s = ei[e]; t = ei[NEX + e]; } else { s = t = e - NEX; }
  int h = lane >> 4, j = lane & 15;
  const float* pl = xl + ((size_t)b * GX + s) * DIMX + h * DHX;
  const float* pr = xr + ((size_t)b * GX + t) * DIMX + h * DHX;
  const float* pa = att + h * DHX;
  float acc = 0.f;
  #pragma unroll
  for (int k = 0; k < 5; ++k) {
    int d = j + 16 * k;
    float u = pl[d] + pr[d];
    u = (u > 0.f) ? u : 0.2f * u;
    acc += u * pa[d];
  }
  acc = grp16_sum(acc);
  if (j == 0) {
    logit[((size_t)b * E2X + e) * NH + h] = acc;
    atomicMax(&lmax[((size_t)b * GX + t) * NH + h], f2o(acc));
  }
}

__global__ void gat_exp_kernel(const int* __restrict__ ei, float* __restrict__ lg,
                               const unsigned* __restrict__ lmax, float* __restrict__ den) {
  int i = blockIdx.x * blockDim.x + threadIdx.x;
  if (i >= BX * E2X * NH) return;
  int h = i & 3; int be = i >> 2; int b = be / E2X, e = be % E2X;
  int t = (e < NEX) ? ei[NEX + e] : e - NEX;
  float m = o2f(lmax[((size_t)b * GX + t) * NH + h]);
  float ex = expf(lg[i] - m);
  lg[i] = ex;
  atomicAdd(&den[((size_t)b * GX + t) * NH + h], ex);
}

__global__ void gat_scatter_kernel(const float* __restrict__ xl, const int* __restrict__ ei,
                                   const float* __restrict__ ex, const float* __restrict__ den,
                                   float* __restrict__ o) {
  int widx = (blockIdx.x * blockDim.x + threadIdx.x) >> 6;
  int lane = threadIdx.x & 63;
  if (widx >= BX * E2X) return;
  int b = widx / E2X, e = widx % E2X;
  int s, t;
  if (e < NEX) { s = ei[e]; t = ei[NEX + e]; } else { s = t = e - NEX; }
  int h = lane >> 4, j = lane & 15;
  float a = ex[((size_t)b * E2X + e) * NH + h] /
            (den[((size_t)b * GX + t) * NH + h] + 1e-16f);
  const float* ps = xl + ((size_t)b * GX + s) * DIMX + h * DHX;
  float* po = o + ((size_t)b * GX + t) * DIMX + h * DHX;
  #pragma unroll
  for (int k = 0; k < 5; ++k) {
    int d = j + 16 * k;
    atomicAdd(&po[d], a * ps[d]);
  }
}

// ---------- LN / performer pieces ----------
__global__ void ln_kernel(const float* __restrict__ x, const float* __restrict__ g,
                          const float* __restrict__ bt, float* __restrict__ y, int rows) {
  int w = (blockIdx.x * blockDim.x + threadIdx.x) >> 6;
  int lane = threadIdx.x & 63;
  if (w >= rows) return;
  const float* p = x + (size_t)w * DIMX;
  float v[5]; float s = 0.f;
  #pragma unroll
  for (int k = 0; k < 5; ++k) { v[k] = p[lane + 64 * k]; s += v[k]; }
  s = wave_sum(s);
  float mean = s * (1.0f / DIMX);
  float s2 = 0.f;
  #pragma unroll
  for (int k = 0; k < 5; ++k) { float d = v[k] - mean; s2 += d * d; }
  s2 = wave_sum(s2);
  float rstd = 1.0f / sqrtf(s2 * (1.0f / DIMX) + 1e-5f);
  #pragma unroll
  for (int k = 0; k < 5; ++k) {
    int d = lane + 64 * k;
    y[(size_t)w * DIMX + d] = (v[k] - mean) * rstd * g[d] + bt[d];
  }
}

__global__ void diag_kernel(const float* __restrict__ x, float* __restrict__ diag, float norm2) {
  int w = (blockIdx.x * blockDim.x + threadIdx.x) >> 6;
  int lane = threadIdx.x & 63;
  if (w >= BGX) return;
  int b = w / GX, n = w % GX;
  int h = lane >> 4, j = lane & 15;
  const float* p = x + (size_t)w * DIMX + h * DHX;
  float s = 0.f;
  #pragma unroll
  for (int k = 0; k < 5; ++k) { float f = p[j + 16 * k]; s += f * f; }
  s = grp16_sum(s);
  if (j == 0) diag[((size_t)b * NH + h) * GX + n] = 0.5f * norm2 * s;
}

// max over one (b,h) slice (relative index blockIdx.y) -> kmax8[bh0+rel]
__global__ void maxred_kernel(const float* __restrict__ dd, unsigned* __restrict__ kmax8, int bh0) {
  int rel = blockIdx.y;
  const float* p = dd + (size_t)rel * GX * NBX;
  const int n = GX * NBX;
  float m = -INFINITY;
  for (int i = blockIdx.x * blockDim.x + threadIdx.x; i < n; i += gridDim.x * blockDim.x)
    m = fmaxf(m, p[i]);
  m = wave_max(m);
  __shared__ float red[4];
  if ((threadIdx.x & 63) == 0) red[threadIdx.x >> 6] = m;
  __syncthreads();
  if (threadIdx.x == 0) {
    float mm = fmaxf(fmaxf(red[0], red[1]), fmaxf(red[2], red[3]));
    atomicMax(&kmax8[bh0 + rel], f2o(mm));
  }
}

__global__ void kexp_kernel(float* __restrict__ dd, const float* __restrict__ diag,
                            const unsigned* __restrict__ kmax8, float ratio, int bh0, int total) {
  int i = blockIdx.x * blockDim.x + threadIdx.x;
  if (i >= total) return;
  int rel = i / (GX * NBX);
  int r = i - rel * (GX * NBX);
  int n = r / NBX;
  int bh = bh0 + rel;
  float m = o2f(kmax8[bh]);
  dd[i] = ratio * (expf(dd[i] - diag[(size_t)bh * GX + n] - m) + 1e-4f);
}

__global__ void ksum_kernel(const float* __restrict__ kp, float* __restrict__ ksum, int bh0) {
  int rel = blockIdx.y;
  const float* p = kp + (size_t)rel * GX * NBX;
  int t = threadIdx.x;
  int n0 = blockIdx.x * 512;
  int n1 = n0 + 512; if (n1 > GX) n1 = GX;
  float a0 = 0.f, a1 = 0.f;
  for (int n = n0; n < n1; ++n) {
    a0 += p[(size_t)n * NBX + t];
    if (t < NBX - 256) a1 += p[(size_t)n * NBX + 256 + t];
  }
  float* ks = ksum + (size_t)(bh0 + rel) * NBX;
  atomicAdd(&ks[t], a0);
  if (t < NBX - 256) atomicAdd(&ks[256 + t], a1);
}

__global__ __launch_bounds__(256)
void ctxm_kernel(const float* __restrict__ kp, const float* __restrict__ v,
                 float* __restrict__ ctxm, int bh0) {
  int rel = blockIdx.z; int bh = bh0 + rel; int b = bh >> 2, h = bh & 3;
  int m0 = blockIdx.x * 64;
  int n0 = blockIdx.y * 1024;
  int n1 = n0 + 1024; if (n1 > GX) n1 = GX;
  __shared__ float skp[4][64];
  __shared__ float sv[4][80];
  const float* kpb = kp + (size_t)rel * GX * NBX;
  const float* vb = v + (size_t)b * GX * DIMX + h * DHX;
  int t = threadIdx.x;
  int tm = t >> 4, td = t & 15;
  float acc[4][5] = {};
  for (int n = n0; n < n1; n += 4) {
    __syncthreads();
    { int r = t >> 6, c = t & 63; int nn = n + r;
      skp[r][c] = (nn < n1 && (m0 + c) < NBX) ? kpb[(size_t)nn * NBX + m0 + c] : 0.f; }
    { int r = t / 80, c = t - r * 80; if (r < 4) { int nn = n + r;
        sv[r][c] = (nn < n1) ? vb[(size_t)nn * DIMX + c] : 0.f; } }
    { int t2 = t + 256; int r = t2 / 80, c = t2 - r * 80; if (t2 < 320) { int nn = n + r;
        sv[r][c] = (nn < n1) ? vb[(size_t)nn * DIMX + c] : 0.f; } }
    __syncthreads();
    #pragma unroll
    for (int r = 0; r < 4; ++r) {
      float kk[4], vv[5];
      #pragma unroll
      for (int im = 0; im < 4; ++im) kk[im] = skp[r][tm * 4 + im];
      #pragma unroll
      for (int id = 0; id < 5; ++id) vv[id] = sv[r][td * 5 + id];
      #pragma unroll
      for (int im = 0; im < 4; ++im)
        #pragma unroll
        for (int id = 0; id < 5; ++id) acc[im][id] += kk[im] * vv[id];
    }
  }
  #pragma unroll
  for (int im = 0; im < 4; ++im) {
    int m = m0 + tm * 4 + im;
    if (m < NBX)
      #pragma unroll
      for (int id = 0; id < 5; ++id)
        atomicAdd(&ctxm[((size_t)bh * NBX + m) * DHX + td * 5 + id], acc[im][id]);
  }
}

__global__ void qexp_kernel(float* __restrict__ dd, const float* __restrict__ diag,
                            const float* __restrict__ ksum, float* __restrict__ dinv,
                            float ratio, int bh0, int nrows) {
  int w = (blockIdx.x * blockDim.x + threadIdx.x) >> 6;
  int lane = threadIdx.x & 63;
  if (w >= nrows) return;
  int rel = w / GX;
  int n = w - rel * GX;
  int bh = bh0 + rel;
  float* p = dd + (size_t)w * NBX;
  const float* ks = ksum + (size_t)bh * NBX;
  float v[6]; float m = -INFINITY;
  #pragma unroll
  for (int k = 0; k < 6; ++k) {
    int i = lane + 64 * k;
    v[k] = (i < NBX) ? p[i] : -INFINITY;
    m = fmaxf(m, v[k]);
  }
  m = wave_max(m);
  float dg = diag[(size_t)bh * GX + n];
  float s = 0.f;
  #pragma unroll
  for (int k = 0; k < 6; ++k) {
    int i = lane + 64 * k;
    if (i < NBX) {
      float e = ratio * (expf(v[k] - dg - m) + 1e-4f);
      p[i] = e;
      s += e * ks[i];
    }
  }
  s = wave_sum(s);
  if (lane == 0) dinv[(size_t)bh * GX + n] = 1.f / s;
}

__global__ void gelu_kernel(float* __restrict__ f, int n) {
  int i = blockIdx.x * blockDim.x + threadIdx.x;
  if (i >= n) return;
  float x = f[i];
  f[i] = 0.5f * x * (1.0f + erff(x * 0.7071067811865476f));
}

__global__ void head_kernel(const float* __restrict__ h, const float* __restrict__ w,
                            const float* __restrict__ b, float* __restrict__ out) {
  int wv = (blockIdx.x * blockDim.x + threadIdx.x) >> 6;
  int lane = threadIdx.x & 63;
  if (wv >= BGX) return;
  const float* p = h + (size_t)wv * DIMX;
  float s = 0.f;
  #pragma unroll
  for (int k = 0; k < 5; ++k) s += p[lane + 64 * k] * w[lane + 64 * k];
  s = wave_sum(s);
  if (lane == 0) out[wv] = s + b[0];
}

// ---------- host ----------
extern "C" void kernel_launch(void* const* d_in, const int* in_sizes, int n_in,
                              void* d_out, int out_size, void* d_ws, size_t ws_size,
                              hipStream_t stream) {
  const int*   idx      = (const int*)  d_in[0];
  const float* x_expr   = (const float*)d_in[1];
  const float* esm2     = (const float*)d_in[2];
  const float* ae_lat   = (const float*)d_in[3];
  const int*   ei       = (const int*)  d_in[4];
  const float* gene_w   = (const float*)d_in[5];
  const float* gene_b   = (const float*)d_in[6];
  const float* ae_w     = (const float*)d_in[7];
  const float* ae_b     = (const float*)d_in[8];
  const float* expr_w   = (const float*)d_in[9];
  const float* expr_b   = (const float*)d_in[10];
  const float* gat_wl   = (const float*)d_in[11];
  const float* gat_bl   = (const float*)d_in[12];
  const float* gat_wr   = (const float*)d_in[13];
  const float* gat_br   = (const float*)d_in[14];
  const float* gat_att  = (const float*)d_in[15];
  const float* gat_bias = (const float*)d_in[16];
  const float* ln1g     = (const float*)d_in[17];
  const float* ln1b     = (const float*)d_in[18];
  const float* wq       = (const float*)d_in[19];
  const float* wk       = (const float*)d_in[20];
  const float* wvv      = (const float*)d_in[21];
  const float* wo       = (const float*)d_in[22];
  const float* bo       = (const float*)d_in[23];
  const float* proj     = (const float*)d_in[24];
  const float* ln2g     = (const float*)d_in[25];
  const float* ln2b     = (const float*)d_in[26];
  const float* w1       = (const float*)d_in[27];
  const float* b1       = (const float*)d_in[28];
  const float* w2       = (const float*)d_in[29];
  const float* b2       = (const float*)d_in[30];
  const float* lng      = (const float*)d_in[31];
  const float* lnb      = (const float*)d_in[32];
  const float* headw    = (const float*)d_in[33];
  const float* headb    = (const float*)d_in[34];
  float* out = (float*)d_out;

  const size_t BGD = (size_t)BGX * DIMX;          // 12,388,480
  const size_t DDS = (size_t)GX * NBX;            // 6,774,950 per (b,h) slice

  float* ws = (float*)d_ws;
  size_t off = 0;
  auto alloc = [&](size_t n) { float* p = ws + off; off += n; return p; };
  float* A0 = alloc(BGD);
  float* A1 = alloc(BGD);
  float* A2 = alloc(BGD);
  float* A3 = alloc(BGD);
  float* f_edge = alloc((size_t)BX * E2X * NH);
  float* f_ctx  = alloc((size_t)BX * DIMX);
  unsigned* u_lmax = (unsigned*)alloc((size_t)BX * GX * NH);
  float* f_den  = alloc((size_t)BX * GX * NH);
  float* f_diag = alloc((size_t)BHX * GX);
  unsigned* u_kmax = (unsigned*)alloc(8);
  float* f_ksum = alloc((size_t)BHX * NBX);
  float* f_ctxm = alloc((size_t)BHX * NBX * DHX);
  float* f_dinv = alloc((size_t)BHX * GX);

  // adaptive dd region: NZ (b,h) slices, 1..8
  size_t avail = ws_size / sizeof(float);
  size_t rem = (avail > off) ? (avail - off) : 0;
  int NZ = (int)(rem / DDS);
  if (NZ < 1) NZ = 1;
  if (NZ > BHX) NZ = BHX;
  float* f_dd = alloc((size_t)NZ * DDS);
  // FF chunk rows reusing the dd region
  int CH = (int)(((size_t)NZ * DDS) / FFX);
  if (CH > BGX) CH = BGX;
  if (CH < 256) CH = 256;

  const float NORM  = 0.33437015248821106f;   // 80^-0.25
  const float RATIO = 0.05345224838248488f;   // 350^-0.5
  const unsigned ORD_NEG_INF = 0x007FFFFFu;   // f2o(-inf)

  auto cdiv = [](int a, int b) { return (a + b - 1) / b; };

  // ---- Stage A: embeddings ----
  // gene = esm2 @ gene_w + gene_b -> A2 (first G rows)
  gemm_kernel<false, true, false, false><<<dim3(cdiv(DIMX, GTN), cdiv(GX, GTM), 1), 256, 0, stream>>>(
      esm2, DIMX, 1, 0, 0, 0, gene_w, DIMX, 0, 0, gene_b, nullptr, 0,
      A2, DIMX, 1, 0, 0, 0, GX, DIMX, DIMX, 1.0f);
  ctx_kernel<<<dim3(5, BX), 64, 0, stream>>>(idx, ae_lat, ae_w, ae_b, f_ctx);
  pre_kernel<<<cdiv(BGX * DIMX, 256), 256, 0, stream>>>(x_expr, A2, f_ctx, A1);
  // x = pre @ expr_w + expr_b -> A0
  gemm_kernel<false, true, false, false><<<dim3(cdiv(DIMX, GTN), cdiv(BGX, GTM), 1), 256, 0, stream>>>(
      A1, DIMX, 1, 0, 0, 0, expr_w, DIMX, 0, 0, expr_b, nullptr, 0,
      A0, DIMX, 1, 0, 0, 0, BGX, DIMX, DIMX, 1.0f);

  // ---- Stage B: GATv2 ----
  // xl -> A1, xr -> A2, out -> A3
  gemm_kernel<false, true, false, false><<<dim3(cdiv(DIMX, GTN), cdiv(BGX, GTM), 1), 256, 0, stream>>>(
      A0, DIMX, 1, 0, 0, 0, gat_wl, DIMX, 0, 0, gat_bl, nullptr, 0,
      A1, DIMX, 1, 0, 0, 0, BGX, DIMX, DIMX, 1.0f);
  gemm_kernel<false, true, false, false><<<dim3(cdiv(DIMX, GTN), cdiv(BGX, GTM), 1), 256, 0, stream>>>(
      A0, DIMX, 1, 0, 0, 0, gat_wr, DIMX, 0, 0, gat_br, nullptr, 0,
      A2, DIMX, 1, 0, 0, 0, BGX, DIMX, DIMX, 1.0f);
  fill_u32_kernel<<<cdiv(BX * GX * NH, 256), 256, 0, stream>>>(u_lmax, ORD_NEG_INF, BX * GX * NH);
  fill_u32_kernel<<<cdiv(BX * GX * NH, 256), 256, 0, stream>>>((unsigned*)f_den, 0u, BX * GX * NH);
  bias_init_kernel<<<cdiv(BGX * DIMX, 256), 256, 0, stream>>>(A3, gat_bias);
  gat_logit_kernel<<<cdiv(BX * E2X, 4), 256, 0, stream>>>(A1, A2, gat_att, ei, f_edge, u_lmax);
  gat_exp_kernel<<<cdiv(BX * E2X * NH, 256), 256, 0, stream>>>(ei, f_edge, u_lmax, f_den);
  gat_scatter_kernel<<<cdiv(BX * E2X, 4), 256, 0, stream>>>(A1, ei, f_edge, f_den, A3);

  // activations now in A3; A0/A1/A2 scratch.

  // ---- Performer layers ----
  for (int l = 0; l < 2; ++l) {
    const float* Wq = wq + (size_t)l * DIMX * DIMX;
    const float* Wk = wk + (size_t)l * DIMX * DIMX;
    const float* Wv = wvv + (size_t)l * DIMX * DIMX;
    const float* Wo = wo + (size_t)l * DIMX * DIMX;
    const float* Bo = bo + (size_t)l * DIMX;
    const float* Pj = proj + (size_t)l * NBX * DHX;
    const float* W1 = w1 + (size_t)l * DIMX * FFX;
    const float* B1 = b1 + (size_t)l * FFX;
    const float* W2 = w2 + (size_t)l * FFX * DIMX;
    const float* B2 = b2 + (size_t)l * DIMX;

    // h = LN(x) -> A0
    ln_kernel<<<cdiv(BGX, 4), 256, 0, stream>>>(A3, ln1g + l * DIMX, ln1b + l * DIMX, A0, BGX);
    // k = h @ Wk -> A1 ; v = h @ Wv -> A2   (no bias!)
    gemm_kernel<false, false, false, false><<<dim3(cdiv(DIMX, GTN), cdiv(BGX, GTM), 1), 256, 0, stream>>>(
        A0, DIMX, 1, 0, 0, 0, Wk, DIMX, 0, 0, nullptr, nullptr, 0,
        A1, DIMX, 1, 0, 0, 0, BGX, DIMX, DIMX, 1.0f);
    gemm_kernel<false, false, false, false><<<dim3(cdiv(DIMX, GTN), cdiv(BGX, GTM), 1), 256, 0, stream>>>(
        A0, DIMX, 1, 0, 0, 0, Wv, DIMX, 0, 0, nullptr, nullptr, 0,
        A2, DIMX, 1, 0, 0, 0, BGX, DIMX, DIMX, 1.0f);

    // ---- k-phase ----
    diag_kernel<<<cdiv(BGX, 4), 256, 0, stream>>>(A1, f_diag, 0.11180339887498948f);
    fill_u32_kernel<<<1, 8, 0, stream>>>(u_kmax, ORD_NEG_INF, 8);
    fill_u32_kernel<<<cdiv(BHX * NBX, 256), 256, 0, stream>>>((unsigned*)f_ksum, 0u, BHX * NBX);
    fill_u32_kernel<<<cdiv(BHX * NBX * DHX, 256), 256, 0, stream>>>((unsigned*)f_ctxm, 0u, BHX * NBX * DHX);
    for (int bh0 = 0; bh0 < BHX; bh0 += NZ) {
      int nz = BHX - bh0 < NZ ? BHX - bh0 : NZ;
      // dd = NORM * k_slice @ Pj^T   (relative C, absolute A)
      gemm_kernel<false, false, true, false><<<dim3(cdiv(NBX, GTN), cdiv(GX, GTM), nz), 256, 0, stream>>>(
          A1, DIMX, NH, (size_t)GX * DIMX, DHX, bh0,
          Pj, DHX, 0, 0, nullptr, nullptr, 0,
          f_dd, NBX, 1, DDS, 0, 0,
          GX, NBX, DHX, NORM);
      maxred_kernel<<<dim3(256, nz), 256, 0, stream>>>(f_dd, u_kmax, bh0);
      kexp_kernel<<<cdiv(nz * (int)DDS, 256), 256, 0, stream>>>(f_dd, f_diag, u_kmax, RATIO, bh0, nz * (int)DDS);
      ksum_kernel<<<dim3(cdiv(GX, 512), nz), 256, 0, stream>>>(f_dd, f_ksum, bh0);
      ctxm_kernel<<<dim3(cdiv(NBX, 64), cdiv(GX, 1024), nz), 256, 0, stream>>>(f_dd, A2, f_ctxm, bh0);
    }

    // q = h @ Wq -> A1 (overwrite k)
    gemm_kernel<false, false, false, false><<<dim3(cdiv(DIMX, GTN), cdiv(BGX, GTM), 1), 256, 0, stream>>>(
        A0, DIMX, 1, 0, 0, 0, Wq, DIMX, 0, 0, nullptr, nullptr, 0,
        A1, DIMX, 1, 0, 0, 0, BGX, DIMX, DIMX, 1.0f);

    // ---- q-phase ----  (o -> A0, overwriting h)
    diag_kernel<<<cdiv(BGX, 4), 256, 0, stream>>>(A1, f_diag, 0.11180339887498948f);
    for (int bh0 = 0; bh0 < BHX; bh0 += NZ) {
      int nz = BHX - bh0 < NZ ? BHX - bh0 : NZ;
      gemm_kernel<false, false, true, false><<<dim3(cdiv(NBX, GTN), cdiv(GX, GTM), nz), 256, 0, stream>>>(
          A1, DIMX, NH, (size_t)GX * DIMX, DHX, bh0,
          Pj, DHX, 0, 0, nullptr, nullptr, 0,
          f_dd, NBX, 1, DDS, 0, 0,
          GX, NBX, DHX, NORM);
      qexp_kernel<<<cdiv(nz * GX, 4), 256, 0, stream>>>(f_dd, f_diag, f_ksum, f_dinv, RATIO, bh0, nz * GX);
      // o_slice = dinv * (qp @ ctxm) -> A0 head slices (absolute C/B, relative A)
      gemm_kernel<false, false, false, true><<<dim3(cdiv(DHX, GTN), cdiv(GX, GTM), nz), 256, 0, stream>>>(
          f_dd, NBX, 1, DDS, 0, 0,
          f_ctxm, DHX, (size_t)NBX * DHX, bh0,
          nullptr, f_dinv, (size_t)GX,
          A0, DIMX, NH, (size_t)GX * DIMX, DHX, bh0,
          GX, DHX, NBX, 1.0f);
    }
    // x += o @ Wo + Bo
    gemm_kernel<true, true, false, false><<<dim3(cdiv(DIMX, GTN), cdiv(BGX, GTM), 1), 256, 0, stream>>>(
        A0, DIMX, 1, 0, 0, 0, Wo, DIMX, 0, 0, Bo, nullptr, 0,
        A3, DIMX, 1, 0, 0, 0, BGX, DIMX, DIMX, 1.0f);

    // ---- FF ----
    ln_kernel<<<cdiv(BGX, 4), 256, 0, stream>>>(A3, ln2g + l * DIMX, ln2b + l * DIMX, A1, BGX);
    for (int r0 = 0; r0 < BGX; r0 += CH) {
      int rows = BGX - r0 < CH ? BGX - r0 : CH;
      gemm_kernel<false, true, false, false><<<dim3(cdiv(FFX, GTN), cdiv(rows, GTM), 1), 256, 0, stream>>>(
          A1 + (size_t)r0 * DIMX, DIMX, 1, 0, 0, 0, W1, FFX, 0, 0, B1, nullptr, 0,
          f_dd, FFX, 1, 0, 0, 0, rows, FFX, DIMX, 1.0f);
      gelu_kernel<<<cdiv(rows * FFX, 256), 256, 0, stream>>>(f_dd, rows * FFX);
      gemm_kernel<true, true, false, false><<<dim3(cdiv(DIMX, GTN), cdiv(rows, GTM), 1), 256, 0, stream>>>(
          f_dd, FFX, 1, 0, 0, 0, W2, DIMX, 0, 0, B2, nullptr, 0,
          A3 + (size_t)r0 * DIMX, DIMX, 1, 0, 0, 0, rows, DIMX, FFX, 1.0f);
    }
  }

  // ---- final LN + head ----
  ln_kernel<<<cdiv(BGX, 4), 256, 0, stream>>>(A3, lng, lnb, A0, BGX);
  head_kernel<<<cdiv(BGX, 4), 256, 0, stream>>>(A0, headw, headb, out);
}

// Round 5
// 9153.313 us; speedup vs baseline: 1.3970x; 1.3970x over previous
//
#include <hip/hip_runtime.h>
#include <cstdint>
#include <math.h>

#define DIMX 320
#define NH 4
#define DHX 80
#define GX 19357
#define NBX 350
#define BX 2
#define NEX 160000
#define E2X (NEX + GX)      // 179357 edges incl. self loops
#define BGX (BX * GX)       // 38714 rows
#define FFX 1280
#define BHX (BX * NH)       // 8

typedef float f32x4 __attribute__((ext_vector_type(4)));
typedef short bf16x4 __attribute__((ext_vector_type(4)));
typedef short bf16x8 __attribute__((ext_vector_type(8)));

// ---------- helpers ----------
__device__ __forceinline__ unsigned f2o(float f) {
  unsigned u = __float_as_uint(f);
  return (u & 0x80000000u) ? ~u : (u | 0x80000000u);
}
__device__ __forceinline__ float o2f(unsigned u) {
  return __uint_as_float((u & 0x80000000u) ? (u & 0x7FFFFFFFu) : ~u);
}
__device__ __forceinline__ float wave_sum(float v) {
  #pragma unroll
  for (int o = 32; o; o >>= 1) v += __shfl_xor(v, o, 64);
  return v;
}
__device__ __forceinline__ float wave_max(float v) {
  #pragma unroll
  for (int o = 32; o; o >>= 1) v = fmaxf(v, __shfl_xor(v, o, 64));
  return v;
}
__device__ __forceinline__ float grp16_sum(float v) {
  #pragma unroll
  for (int o = 8; o; o >>= 1) v += __shfl_xor(v, o, 64);
  return v;
}
__device__ __forceinline__ short f2bf(float f) {   // fp32 -> bf16 RNE
  unsigned u = __float_as_uint(f);
  u += 0x7FFFu + ((u >> 16) & 1u);
  return (short)(u >> 16);
}
__device__ __forceinline__ float gelu1(float x) {
  return 0.5f * x * (1.0f + erff(x * 0.7071067811865476f));
}

// ---------- bf16-MFMA GEMM: C = [C +] [gelu](alpha*(A @ B[^T]) [*rowscale] [+ bias]) ----------
// fp32 in HBM; cast to bf16 during LDS staging; fp32 accumulate via
// v_mfma_f32_16x16x32_bf16. block 256 = 4 waves (2x2), tile 128(M) x 64(N), BK=32.
// Fragment layout (guide §3/m156): operand lane l holds (idx=l&15, k=(l>>4)*4+(i&3)+16*(i>>2));
// C/D: col=l&15, row=(l>>4)*4+reg (m89-verified).
#define GTM 128
#define GTN 64
#define GTK 32
#define LPAD 4
template<bool ADD_C, bool HAS_BIAS, bool TRANS_B, bool ROW_SCALE, bool DO_GELU, bool DO_MAX>
__global__ __launch_bounds__(256)
void gemm_bf16_kernel(const float* __restrict__ A, int lda, int Adiv, size_t Ab_hi, size_t Ab_lo, int zA0,
                      const float* __restrict__ Bm, int ldb, size_t Bb, int zB0,
                      const float* __restrict__ bias,
                      const float* __restrict__ rs, size_t rs_stride,
                      unsigned* __restrict__ gmax, int gmax0,
                      float* __restrict__ C, int ldc, int Cdiv, size_t Cb_hi, size_t Cb_lo, int zC0,
                      int M, int N, int K, float alpha)
{
  int bz = blockIdx.z;
  int za = zA0 + bz, zb = zB0 + bz, zc = zC0 + bz;
  A  += (size_t)(za / Adiv) * Ab_hi + (size_t)(za % Adiv) * Ab_lo;
  Bm += (size_t)zb * Bb;
  C  += (size_t)(zc / Cdiv) * Cb_hi + (size_t)(zc % Cdiv) * Cb_lo;
  const float* rsz = ROW_SCALE ? (rs + (size_t)zc * rs_stride) : nullptr;

  __shared__ __align__(16) short As[GTM][GTK + LPAD];
  __shared__ __align__(16) short Bs[GTN][GTK + LPAD];   // stored [n][k]

  int tid = threadIdx.x;
  int wave = tid >> 6, lane = tid & 63;
  int l15 = lane & 15, lg = lane >> 4;
  int wm = (wave >> 1) * 64;   // 0 / 64
  int wn = (wave & 1) * 32;    // 0 / 32
  int row0 = blockIdx.y * GTM, col0 = blockIdx.x * GTN;

  f32x4 acc[4][2];
  #pragma unroll
  for (int i = 0; i < 4; ++i)
    #pragma unroll
    for (int j = 0; j < 2; ++j) acc[i][j] = (f32x4){0.f, 0.f, 0.f, 0.f};

  for (int k0 = 0; k0 < K; k0 += GTK) {
    // ---- stage A tile: 128x32, thread t -> row t>>1, 16 k's ----
    {
      int m = tid >> 1, kk = (tid & 1) * 16;
      int gm = row0 + m;
      const float* ap = A + (size_t)gm * lda + (k0 + kk);
      short tmp[16];
      if (gm < M && (k0 + kk + 16) <= K) {
        #pragma unroll
        for (int j = 0; j < 8; ++j) {
          float2 v = *(const float2*)(ap + 2 * j);
          tmp[2 * j] = f2bf(v.x); tmp[2 * j + 1] = f2bf(v.y);
        }
      } else {
        #pragma unroll
        for (int j = 0; j < 16; ++j) {
          int gk = k0 + kk + j;
          tmp[j] = (gm < M && gk < K) ? f2bf(ap[j]) : (short)0;
        }
      }
      #pragma unroll
      for (int j = 0; j < 4; ++j)
        *(bf16x4*)&As[m][kk + 4 * j] = *(const bf16x4*)&tmp[4 * j];
    }
    // ---- stage B tile into Bs[n][k] ----
    if (TRANS_B) {
      // B is [N,K] row-major (k contiguous)
      int n = tid >> 2, kk = (tid & 3) * 8;
      int gn = col0 + n;
      const float* bp = Bm + (size_t)gn * ldb + (k0 + kk);
      short tmp[8];
      if (gn < N && (k0 + kk + 8) <= K) {
        #pragma unroll
        for (int j = 0; j < 2; ++j) {
          float4 v = *(const float4*)(bp + 4 * j);
          tmp[4 * j] = f2bf(v.x); tmp[4 * j + 1] = f2bf(v.y);
          tmp[4 * j + 2] = f2bf(v.z); tmp[4 * j + 3] = f2bf(v.w);
        }
      } else {
        #pragma unroll
        for (int j = 0; j < 8; ++j) {
          int gk = k0 + kk + j;
          tmp[j] = (gn < N && gk < K) ? f2bf(bp[j]) : (short)0;
        }
      }
      *(bf16x4*)&Bs[n][kk]     = *(const bf16x4*)&tmp[0];
      *(bf16x4*)&Bs[n][kk + 4] = *(const bf16x4*)&tmp[4];
    } else {
      // B is [K,N] row-major (n contiguous) -> transpose while staging
      #pragma unroll
      for (int r = 0; r < 2; ++r) {
        int krow = (tid >> 4) + r * 16;
        int gk = k0 + krow;
        int n4 = (tid & 15) * 4;
        int gn0 = col0 + n4;
        float vv[4];
        if (gk < K && (gn0 + 4) <= N) {
          float4 v = *(const float4*)(Bm + (size_t)gk * ldb + gn0);
          vv[0] = v.x; vv[1] = v.y; vv[2] = v.z; vv[3] = v.w;
        } else {
          #pragma unroll
          for (int j = 0; j < 4; ++j)
            vv[j] = (gk < K && (gn0 + j) < N) ? Bm[(size_t)gk * ldb + gn0 + j] : 0.f;
        }
        #pragma unroll
        for (int j = 0; j < 4; ++j) Bs[n4 + j][krow] = f2bf(vv[j]);
      }
    }
    __syncthreads();

    // ---- fragments + MFMA ----
    bf16x8 afr[4], bfr[2];
    #pragma unroll
    for (int nt = 0; nt < 2; ++nt) {
      int n = wn + nt * 16 + l15;
      bf16x4 lo = *(const bf16x4*)&Bs[n][lg * 4];
      bf16x4 hi = *(const bf16x4*)&Bs[n][lg * 4 + 16];
      bf16x8 f;
      f[0] = lo[0]; f[1] = lo[1]; f[2] = lo[2]; f[3] = lo[3];
      f[4] = hi[0]; f[5] = hi[1]; f[6] = hi[2]; f[7] = hi[3];
      bfr[nt] = f;
    }
    #pragma unroll
    for (int mt = 0; mt < 4; ++mt) {
      int m = wm + mt * 16 + l15;
      bf16x4 lo = *(const bf16x4*)&As[m][lg * 4];
      bf16x4 hi = *(const bf16x4*)&As[m][lg * 4 + 16];
      bf16x8 f;
      f[0] = lo[0]; f[1] = lo[1]; f[2] = lo[2]; f[3] = lo[3];
      f[4] = hi[0]; f[5] = hi[1]; f[6] = hi[2]; f[7] = hi[3];
      afr[mt] = f;
    }
    #pragma unroll
    for (int mt = 0; mt < 4; ++mt)
      #pragma unroll
      for (int nt = 0; nt < 2; ++nt)
        acc[mt][nt] = __builtin_amdgcn_mfma_f32_16x16x32_bf16(afr[mt], bfr[nt], acc[mt][nt], 0, 0, 0);
    __syncthreads();
  }

  // ---- epilogue ----
  float lmax = -INFINITY;
  #pragma unroll
  for (int mt = 0; mt < 4; ++mt) {
    #pragma unroll
    for (int nt = 0; nt < 2; ++nt) {
      f32x4 a = acc[mt][nt];
      int gn = col0 + wn + nt * 16 + l15;
      #pragma unroll
      for (int r = 0; r < 4; ++r) {
        int gm = row0 + wm + mt * 16 + lg * 4 + r;
        if (gm < M && gn < N) {
          float v = alpha * a[r];
          if (DO_MAX) lmax = fmaxf(lmax, v);
          if (ROW_SCALE) v *= rsz[gm];
          if (HAS_BIAS) v += bias[gn];
          if (DO_GELU) v = gelu1(v);
          if (ADD_C) v += C[(size_t)gm * ldc + gn];
          C[(size_t)gm * ldc + gn] = v;
        }
      }
    }
  }
  if (DO_MAX) {
    lmax = wave_max(lmax);
    if (lane == 0) atomicMax(&gmax[gmax0 + bz], f2o(lmax));
  }
}

// ---------- small kernels ----------
__global__ void fill_u32_kernel(unsigned* __restrict__ p, unsigned v, int n) {
  int i = blockIdx.x * blockDim.x + threadIdx.x;
  if (i < n) p[i] = v;
}

__global__ void ctx_kernel(const int* __restrict__ idx, const float* __restrict__ ae,
                           const float* __restrict__ w, const float* __restrict__ b,
                           float* __restrict__ ctx) {
  int bb = blockIdx.y;
  int n = blockIdx.x * 64 + threadIdx.x;
  if (n >= DIMX) return;
  const float* a = ae + (size_t)idx[bb] * DIMX;
  float s = b[n];
  for (int k = 0; k < DIMX; ++k) s += a[k] * w[(size_t)k * DIMX + n];
  ctx[bb * DIMX + n] = s;
}

__global__ void pre_kernel(const float* __restrict__ x_expr, const float* __restrict__ gene,
                           const float* __restrict__ ctx, float* __restrict__ pre) {
  int i = blockIdx.x * blockDim.x + threadIdx.x;
  if (i >= BGX * DIMX) return;
  int d = i % DIMX;
  int bg = i / DIMX;
  int b = bg / GX, g = bg % GX;
  float xv = x_expr[bg];
  int ii = (d < DIMX / 2) ? (d + 1) : (d - DIMX / 2 + 1);
  float theta = exp2f(6.643856189774724f * ((float)ii * (1.0f / 160.0f)));
  float ang = xv * theta;
  float r = (d < DIMX / 2) ? sinf(ang) : cosf(ang);
  pre[i] = r + gene[(size_t)g * DIMX + d] + ctx[b * DIMX + d];
}

__global__ void bias_init_kernel(float* __restrict__ o, const float* __restrict__ b) {
  int i = blockIdx.x * blockDim.x + threadIdx.x;
  if (i >= BGX * DIMX) return;
  o[i] = b[i % DIMX];
}

// ---------- GAT ----------
__global__ void gat_logit_kernel(const float* __restrict__ xl, const float* __restrict__ xr,
                                 const float* __restrict__ att, const int* __restrict__ ei,
                                 float* __restrict__ logit, unsigned* __restrict__ lmax) {
  int widx = (blockIdx.x * blockDim.x + threadIdx.x) >> 6;
  int lane = threadIdx.x & 63;
  if (widx >= BX * E2X) return;
  int b = widx / E2X, e = widx % E2X;
  int s, t;
  if (e < NEX) { s = ei[e]; t = ei[NEX + e]; } else { s = t = e - NEX; }
  int h = lane >> 4, j = lane & 15;
  const float* pl = xl + ((size_t)b * GX + s) * DIMX + h * DHX;
  const float* pr = xr + ((size_t)b * GX + t) * DIMX + h * DHX;
  const float* pa = att + h * DHX;
  float acc = 0.f;
  #pragma unroll
  for (int k = 0; k < 5; ++k) {
    int d = j + 16 * k;
    float u = pl[d] + pr[d];
    u = (u > 0.f) ? u : 0.2f * u;
    acc += u * pa[d];
  }
  acc = grp16_sum(acc);
  if (j == 0) {
    logit[((size_t)b * E2X + e) * NH + h] = acc;
    atomicMax(&lmax[((size_t)b * GX + t) * NH + h], f2o(acc));
  }
}

__global__ void gat_exp_kernel(const int* __restrict__ ei, float* __restrict__ lg,
                               const unsigned* __restrict__ lmax, float* __restrict__ den) {
  int i = blockIdx.x * blockDim.x + threadIdx.x;
  if (i >= BX * E2X * NH) return;
  int h = i & 3; int be = i >> 2; int b = be / E2X, e = be % E2X;
  int t = (e < NEX) ? ei[NEX + e] : e - NEX;
  float m = o2f(lmax[((size_t)b * GX + t) * NH + h]);
  float ex = expf(lg[i] - m);
  lg[i] = ex;
  atomicAdd(&den[((size_t)b * GX + t) * NH + h], ex);
}

__global__ void gat_scatter_kernel(const float* __restrict__ xl, const int* __restrict__ ei,
                                   const float* __restrict__ ex, const float* __restrict__ den,
                                   float* __restrict__ o) {
  int widx = (blockIdx.x * blockDim.x + threadIdx.x) >> 6;
  int lane = threadIdx.x & 63;
  if (widx >= BX * E2X) return;
  int b = widx / E2X, e = widx % E2X;
  int s, t;
  if (e < NEX) { s = ei[e]; t = ei[NEX + e]; } else { s = t = e - NEX; }
  int h = lane >> 4, j = lane & 15;
  float a = ex[((size_t)b * E2X + e) * NH + h] /
            (den[((size_t)b * GX + t) * NH + h] + 1e-16f);
  const float* ps = xl + ((size_t)b * GX + s) * DIMX + h * DHX;
  float* po = o + ((size_t)b * GX + t) * DIMX + h * DHX;
  #pragma unroll
  for (int k = 0; k < 5; ++k) {
    int d = j + 16 * k;
    atomicAdd(&po[d], a * ps[d]);
  }
}

// ---------- LN / performer pieces ----------
__global__ void ln_kernel(const float* __restrict__ x, const float* __restrict__ g,
                          const float* __restrict__ bt, float* __restrict__ y, int rows) {
  int w = (blockIdx.x * blockDim.x + threadIdx.x) >> 6;
  int lane = threadIdx.x & 63;
  if (w >= rows) return;
  const float* p = x + (size_t)w * DIMX;
  float v[5]; float s = 0.f;
  #pragma unroll
  for (int k = 0; k < 5; ++k) { v[k] = p[lane + 64 * k]; s += v[k]; }
  s = wave_sum(s);
  float mean = s * (1.0f / DIMX);
  float s2 = 0.f;
  #pragma unroll
  for (int k = 0; k < 5; ++k) { float d = v[k] - mean; s2 += d * d; }
  s2 = wave_sum(s2);
  float rstd = 1.0f / sqrtf(s2 * (1.0f / DIMX) + 1e-5f);
  #pragma unroll
  for (int k = 0; k < 5; ++k) {
    int d = lane + 64 * k;
    y[(size_t)w * DIMX + d] = (v[k] - mean) * rstd * g[d] + bt[d];
  }
}

__global__ void diag_kernel(const float* __restrict__ x, float* __restrict__ diag, float norm2) {
  int w = (blockIdx.x * blockDim.x + threadIdx.x) >> 6;
  int lane = threadIdx.x & 63;
  if (w >= BGX) return;
  int b = w / GX, n = w % GX;
  int h = lane >> 4, j = lane & 15;
  const float* p = x + (size_t)w * DIMX + h * DHX;
  float s = 0.f;
  #pragma unroll
  for (int k = 0; k < 5; ++k) { float f = p[j + 16 * k]; s += f * f; }
  s = grp16_sum(s);
  if (j == 0) diag[((size_t)b * NH + h) * GX + n] = 0.5f * norm2 * s;
}

// fused kexp + column-sum: kp = ratio*(exp(dd - diag - m)+eps) in place; ksum += col sums
__global__ void kexpsum_kernel(float* __restrict__ dd, const float* __restrict__ diag,
                               const unsigned* __restrict__ kmax8, float* __restrict__ ksum,
                               float ratio, int bh0) {
  int rel = blockIdx.y;
  int bh = bh0 + rel;
  float* p = dd + (size_t)rel * GX * NBX;
  const float* dg = diag + (size_t)bh * GX;
  float m = o2f(kmax8[bh]);
  int t = threadIdx.x;
  int n0 = blockIdx.x * 512;
  int n1 = n0 + 512; if (n1 > GX) n1 = GX;
  float a0 = 0.f, a1 = 0.f;
  for (int n = n0; n < n1; ++n) {
    float d = dg[n];
    size_t base = (size_t)n * NBX;
    float e0 = ratio * (expf(p[base + t] - d - m) + 1e-4f);
    p[base + t] = e0; a0 += e0;
    if (t < NBX - 256) {
      float e1 = ratio * (expf(p[base + 256 + t] - d - m) + 1e-4f);
      p[base + 256 + t] = e1; a1 += e1;
    }
  }
  float* ks = ksum + (size_t)bh * NBX;
  atomicAdd(&ks[t], a0);
  if (t < NBX - 256) atomicAdd(&ks[256 + t], a1);
}

__global__ __launch_bounds__(256)
void ctxm_kernel(const float* __restrict__ kp, const float* __restrict__ v,
                 float* __restrict__ ctxm, int bh0) {
  int rel = blockIdx.z; int bh = bh0 + rel; int b = bh >> 2, h = bh & 3;
  int m0 = blockIdx.x * 64;
  int n0 = blockIdx.y * 1024;
  int n1 = n0 + 1024; if (n1 > GX) n1 = GX;
  __shared__ float skp[4][64];
  __shared__ float sv[4][80];
  const float* kpb = kp + (size_t)rel * GX * NBX;
  const float* vb = v + (size_t)b * GX * DIMX + h * DHX;
  int t = threadIdx.x;
  int tm = t >> 4, td = t & 15;
  float acc[4][5] = {};
  for (int n = n0; n < n1; n += 4) {
    __syncthreads();
    { int r = t >> 6, c = t & 63; int nn = n + r;
      skp[r][c] = (nn < n1 && (m0 + c) < NBX) ? kpb[(size_t)nn * NBX + m0 + c] : 0.f; }
    { int r = t / 80, c = t - r * 80; if (r < 4) { int nn = n + r;
        sv[r][c] = (nn < n1) ? vb[(size_t)nn * DIMX + c] : 0.f; } }
    { int t2 = t + 256; int r = t2 / 80, c = t2 - r * 80; if (t2 < 320) { int nn = n + r;
        sv[r][c] = (nn < n1) ? vb[(size_t)nn * DIMX + c] : 0.f; } }
    __syncthreads();
    #pragma unroll
    for (int r = 0; r < 4; ++r) {
      float kk[4], vv[5];
      #pragma unroll
      for (int im = 0; im < 4; ++im) kk[im] = skp[r][tm * 4 + im];
      #pragma unroll
      for (int id = 0; id < 5; ++id) vv[id] = sv[r][td * 5 + id];
      #pragma unroll
      for (int im = 0; im < 4; ++im)
        #pragma unroll
        for (int id = 0; id < 5; ++id) acc[im][id] += kk[im] * vv[id];
    }
  }
  #pragma unroll
  for (int im = 0; im < 4; ++im) {
    int m = m0 + tm * 4 + im;
    if (m < NBX)
      #pragma unroll
      for (int id = 0; id < 5; ++id)
        atomicAdd(&ctxm[((size_t)bh * NBX + m) * DHX + td * 5 + id], acc[im][id]);
  }
}

__global__ void qexp_kernel(float* __restrict__ dd, const float* __restrict__ diag,
                            const float* __restrict__ ksum, float* __restrict__ dinv,
                            float ratio, int bh0, int nrows) {
  int w = (blockIdx.x * blockDim.x + threadIdx.x) >> 6;
  int lane = threadIdx.x & 63;
  if (w >= nrows) return;
  int rel = w / GX;
  int n = w - rel * GX;
  int bh = bh0 + rel;
  float* p = dd + (size_t)w * NBX;
  const float* ks = ksum + (size_t)bh * NBX;
  float v[6]; float m = -INFINITY;
  #pragma unroll
  for (int k = 0; k < 6; ++k) {
    int i = lane + 64 * k;
    v[k] = (i < NBX) ? p[i] : -INFINITY;
    m = fmaxf(m, v[k]);
  }
  m = wave_max(m);
  float dg = diag[(size_t)bh * GX + n];
  float s = 0.f;
  #pragma unroll
  for (int k = 0; k < 6; ++k) {
    int i = lane + 64 * k;
    if (i < NBX) {
      float e = ratio * (expf(v[k] - dg - m) + 1e-4f);
      p[i] = e;
      s += e * ks[i];
    }
  }
  s = wave_sum(s);
  if (lane == 0) dinv[(size_t)bh * GX + n] = 1.f / s;
}

__global__ void head_kernel(const float* __restrict__ h, const float* __restrict__ w,
                            const float* __restrict__ b, float* __restrict__ out) {
  int wv = (blockIdx.x * blockDim.x + threadIdx.x) >> 6;
  int lane = threadIdx.x & 63;
  if (wv >= BGX) return;
  const float* p = h + (size_t)wv * DIMX;
  float s = 0.f;
  #pragma unroll
  for (int k = 0; k < 5; ++k) s += p[lane + 64 * k] * w[lane + 64 * k];
  s = wave_sum(s);
  if (lane == 0) out[wv] = s + b[0];
}

// ---------- host ----------
extern "C" void kernel_launch(void* const* d_in, const int* in_sizes, int n_in,
                              void* d_out, int out_size, void* d_ws, size_t ws_size,
                              hipStream_t stream) {
  const int*   idx      = (const int*)  d_in[0];
  const float* x_expr   = (const float*)d_in[1];
  const float* esm2     = (const float*)d_in[2];
  const float* ae_lat   = (const float*)d_in[3];
  const int*   ei       = (const int*)  d_in[4];
  const float* gene_w   = (const float*)d_in[5];
  const float* gene_b   = (const float*)d_in[6];
  const float* ae_w     = (const float*)d_in[7];
  const float* ae_b     = (const float*)d_in[8];
  const float* expr_w   = (const float*)d_in[9];
  const float* expr_b   = (const float*)d_in[10];
  const float* gat_wl   = (const float*)d_in[11];
  const float* gat_bl   = (const float*)d_in[12];
  const float* gat_wr   = (const float*)d_in[13];
  const float* gat_br   = (const float*)d_in[14];
  const float* gat_att  = (const float*)d_in[15];
  const float* gat_bias = (const float*)d_in[16];
  const float* ln1g     = (const float*)d_in[17];
  const float* ln1b     = (const float*)d_in[18];
  const float* wq       = (const float*)d_in[19];
  const float* wk       = (const float*)d_in[20];
  const float* wvv      = (const float*)d_in[21];
  const float* wo       = (const float*)d_in[22];
  const float* bo       = (const float*)d_in[23];
  const float* proj     = (const float*)d_in[24];
  const float* ln2g     = (const float*)d_in[25];
  const float* ln2b     = (const float*)d_in[26];
  const float* w1       = (const float*)d_in[27];
  const float* b1       = (const float*)d_in[28];
  const float* w2       = (const float*)d_in[29];
  const float* b2       = (const float*)d_in[30];
  const float* lng      = (const float*)d_in[31];
  const float* lnb      = (const float*)d_in[32];
  const float* headw    = (const float*)d_in[33];
  const float* headb    = (const float*)d_in[34];
  float* out = (float*)d_out;

  const size_t BGD = (size_t)BGX * DIMX;
  const size_t DDS = (size_t)GX * NBX;

  float* ws = (float*)d_ws;
  size_t off = 0;
  auto alloc = [&](size_t n) { float* p = ws + off; off += n; return p; };
  float* A0 = alloc(BGD);
  float* A1 = alloc(BGD);
  float* A2 = alloc(BGD);
  float* A3 = alloc(BGD);
  float* f_edge = alloc((size_t)BX * E2X * NH);
  float* f_ctx  = alloc((size_t)BX * DIMX);
  unsigned* u_lmax = (unsigned*)alloc((size_t)BX * GX * NH);
  float* f_den  = alloc((size_t)BX * GX * NH);
  float* f_diag = alloc((size_t)BHX * GX);
  unsigned* u_kmax = (unsigned*)alloc(8);
  float* f_ksum = alloc((size_t)BHX * NBX);
  float* f_ctxm = alloc((size_t)BHX * NBX * DHX);
  float* f_dinv = alloc((size_t)BHX * GX);

  size_t avail = ws_size / sizeof(float);
  size_t rem = (avail > off) ? (avail - off) : 0;
  int NZ = (int)(rem / DDS);
  if (NZ < 1) NZ = 1;
  if (NZ > BHX) NZ = BHX;
  float* f_dd = alloc((size_t)NZ * DDS);
  int CH = (int)(((size_t)NZ * DDS) / FFX);
  if (CH > BGX) CH = BGX;
  if (CH < 256) CH = 256;

  const float NORM  = 0.33437015248821106f;   // 80^-0.25
  const float RATIO = 0.05345224838248488f;   // 350^-0.5
  const unsigned ORD_NEG_INF = 0x007FFFFFu;

  auto cdiv = [](int a, int b) { return (a + b - 1) / b; };

  // ---- Stage A: embeddings ----
  gemm_bf16_kernel<false, true, false, false, false, false>
      <<<dim3(cdiv(DIMX, GTN), cdiv(GX, GTM), 1), 256, 0, stream>>>(
      esm2, DIMX, 1, 0, 0, 0, gene_w, DIMX, 0, 0, gene_b, nullptr, 0, nullptr, 0,
      A2, DIMX, 1, 0, 0, 0, GX, DIMX, DIMX, 1.0f);
  ctx_kernel<<<dim3(5, BX), 64, 0, stream>>>(idx, ae_lat, ae_w, ae_b, f_ctx);
  pre_kernel<<<cdiv(BGX * DIMX, 256), 256, 0, stream>>>(x_expr, A2, f_ctx, A1);
  gemm_bf16_kernel<false, true, false, false, false, false>
      <<<dim3(cdiv(DIMX, GTN), cdiv(BGX, GTM), 1), 256, 0, stream>>>(
      A1, DIMX, 1, 0, 0, 0, expr_w, DIMX, 0, 0, expr_b, nullptr, 0, nullptr, 0,
      A0, DIMX, 1, 0, 0, 0, BGX, DIMX, DIMX, 1.0f);

  // ---- Stage B: GATv2 ----
  gemm_bf16_kernel<false, true, false, false, false, false>
      <<<dim3(cdiv(DIMX, GTN), cdiv(BGX, GTM), 1), 256, 0, stream>>>(
      A0, DIMX, 1, 0, 0, 0, gat_wl, DIMX, 0, 0, gat_bl, nullptr, 0, nullptr, 0,
      A1, DIMX, 1, 0, 0, 0, BGX, DIMX, DIMX, 1.0f);
  gemm_bf16_kernel<false, true, false, false, false, false>
      <<<dim3(cdiv(DIMX, GTN), cdiv(BGX, GTM), 1), 256, 0, stream>>>(
      A0, DIMX, 1, 0, 0, 0, gat_wr, DIMX, 0, 0, gat_br, nullptr, 0, nullptr, 0,
      A2, DIMX, 1, 0, 0, 0, BGX, DIMX, DIMX, 1.0f);
  fill_u32_kernel<<<cdiv(BX * GX * NH, 256), 256, 0, stream>>>(u_lmax, ORD_NEG_INF, BX * GX * NH);
  fill_u32_kernel<<<cdiv(BX * GX * NH, 256), 256, 0, stream>>>((unsigned*)f_den, 0u, BX * GX * NH);
  bias_init_kernel<<<cdiv(BGX * DIMX, 256), 256, 0, stream>>>(A3, gat_bias);
  gat_logit_kernel<<<cdiv(BX * E2X, 4), 256, 0, stream>>>(A1, A2, gat_att, ei, f_edge, u_lmax);
  gat_exp_kernel<<<cdiv(BX * E2X * NH, 256), 256, 0, stream>>>(ei, f_edge, u_lmax, f_den);
  gat_scatter_kernel<<<cdiv(BX * E2X, 4), 256, 0, stream>>>(A1, ei, f_edge, f_den, A3);

  // ---- Performer layers ----
  for (int l = 0; l < 2; ++l) {
    const float* Wq = wq + (size_t)l * DIMX * DIMX;
    const float* Wk = wk + (size_t)l * DIMX * DIMX;
    const float* Wv = wvv + (size_t)l * DIMX * DIMX;
    const float* Wo = wo + (size_t)l * DIMX * DIMX;
    const float* Bo = bo + (size_t)l * DIMX;
    const float* Pj = proj + (size_t)l * NBX * DHX;
    const float* W1 = w1 + (size_t)l * DIMX * FFX;
    const float* B1 = b1 + (size_t)l * FFX;
    const float* W2 = w2 + (size_t)l * FFX * DIMX;
    const float* B2 = b2 + (size_t)l * DIMX;

    ln_kernel<<<cdiv(BGX, 4), 256, 0, stream>>>(A3, ln1g + l * DIMX, ln1b + l * DIMX, A0, BGX);
    gemm_bf16_kernel<false, false, false, false, false, false>
        <<<dim3(cdiv(DIMX, GTN), cdiv(BGX, GTM), 1), 256, 0, stream>>>(
        A0, DIMX, 1, 0, 0, 0, Wk, DIMX, 0, 0, nullptr, nullptr, 0, nullptr, 0,
        A1, DIMX, 1, 0, 0, 0, BGX, DIMX, DIMX, 1.0f);
    gemm_bf16_kernel<false, false, false, false, false, false>
        <<<dim3(cdiv(DIMX, GTN), cdiv(BGX, GTM), 1), 256, 0, stream>>>(
        A0, DIMX, 1, 0, 0, 0, Wv, DIMX, 0, 0, nullptr, nullptr, 0, nullptr, 0,
        A2, DIMX, 1, 0, 0, 0, BGX, DIMX, DIMX, 1.0f);

    // ---- k-phase ----
    diag_kernel<<<cdiv(BGX, 4), 256, 0, stream>>>(A1, f_diag, 0.11180339887498948f);
    fill_u32_kernel<<<1, 8, 0, stream>>>(u_kmax, ORD_NEG_INF, 8);
    fill_u32_kernel<<<cdiv(BHX * NBX, 256), 256, 0, stream>>>((unsigned*)f_ksum, 0u, BHX * NBX);
    fill_u32_kernel<<<cdiv(BHX * NBX * DHX, 256), 256, 0, stream>>>((unsigned*)f_ctxm, 0u, BHX * NBX * DHX);
    for (int bh0 = 0; bh0 < BHX; bh0 += NZ) {
      int nz = BHX - bh0 < NZ ? BHX - bh0 : NZ;
      gemm_bf16_kernel<false, false, true, false, false, true>
          <<<dim3(cdiv(NBX, GTN), cdiv(GX, GTM), nz), 256, 0, stream>>>(
          A1, DIMX, NH, (size_t)GX * DIMX, DHX, bh0,
          Pj, DHX, 0, 0, nullptr, nullptr, 0, u_kmax, bh0,
          f_dd, NBX, 1, DDS, 0, 0,
          GX, NBX, DHX, NORM);
      kexpsum_kernel<<<dim3(cdiv(GX, 512), nz), 256, 0, stream>>>(f_dd, f_diag, u_kmax, f_ksum, RATIO, bh0);
      ctxm_kernel<<<dim3(cdiv(NBX, 64), cdiv(GX, 1024), nz), 256, 0, stream>>>(f_dd, A2, f_ctxm, bh0);
    }

    gemm_bf16_kernel<false, false, false, false, false, false>
        <<<dim3(cdiv(DIMX, GTN), cdiv(BGX, GTM), 1), 256, 0, stream>>>(
        A0, DIMX, 1, 0, 0, 0, Wq, DIMX, 0, 0, nullptr, nullptr, 0, nullptr, 0,
        A1, DIMX, 1, 0, 0, 0, BGX, DIMX, DIMX, 1.0f);

    // ---- q-phase ----
    diag_kernel<<<cdiv(BGX, 4), 256, 0, stream>>>(A1, f_diag, 0.11180339887498948f);
    for (int bh0 = 0; bh0 < BHX; bh0 += NZ) {
      int nz = BHX - bh0 < NZ ? BHX - bh0 : NZ;
      gemm_bf16_kernel<false, false, true, false, false, false>
          <<<dim3(cdiv(NBX, GTN), cdiv(GX, GTM), nz), 256, 0, stream>>>(
          A1, DIMX, NH, (size_t)GX * DIMX, DHX, bh0,
          Pj, DHX, 0, 0, nullptr, nullptr, 0, nullptr, 0,
          f_dd, NBX, 1, DDS, 0, 0,
          GX, NBX, DHX, NORM);
      qexp_kernel<<<cdiv(nz * GX, 4), 256, 0, stream>>>(f_dd, f_diag, f_ksum, f_dinv, RATIO, bh0, nz * GX);
      gemm_bf16_kernel<false, false, false, true, false, false>
          <<<dim3(cdiv(DHX, GTN), cdiv(GX, GTM), nz), 256, 0, stream>>>(
          f_dd, NBX, 1, DDS, 0, 0,
          f_ctxm, DHX, (size_t)NBX * DHX, bh0,
          nullptr, f_dinv, (size_t)GX, nullptr, 0,
          A0, DIMX, NH, (size_t)GX * DIMX, DHX, bh0,
          GX, DHX, NBX, 1.0f);
    }
    gemm_bf16_kernel<true, true, false, false, false, false>
        <<<dim3(cdiv(DIMX, GTN), cdiv(BGX, GTM), 1), 256, 0, stream>>>(
        A0, DIMX, 1, 0, 0, 0, Wo, DIMX, 0, 0, Bo, nullptr, 0, nullptr, 0,
        A3, DIMX, 1, 0, 0, 0, BGX, DIMX, DIMX, 1.0f);

    // ---- FF (GELU fused into FF1 epilogue) ----
    ln_kernel<<<cdiv(BGX, 4), 256, 0, stream>>>(A3, ln2g + l * DIMX, ln2b + l * DIMX, A1, BGX);
    for (int r0 = 0; r0 < BGX; r0 += CH) {
      int rows = BGX - r0 < CH ? BGX - r0 : CH;
      gemm_bf16_kernel<false, true, false, false, true, false>
          <<<dim3(cdiv(FFX, GTN), cdiv(rows, GTM), 1), 256, 0, stream>>>(
          A1 + (size_t)r0 * DIMX, DIMX, 1, 0, 0, 0, W1, FFX, 0, 0, B1, nullptr, 0, nullptr, 0,
          f_dd, FFX, 1, 0, 0, 0, rows, FFX, DIMX, 1.0f);
      gemm_bf16_kernel<true, true, false, false, false, false>
          <<<dim3(cdiv(DIMX, GTN), cdiv(rows, GTM), 1), 256, 0, stream>>>(
          f_dd, FFX, 1, 0, 0, 0, W2, DIMX, 0, 0, B2, nullptr, 0, nullptr, 0,
          A3 + (size_t)r0 * DIMX, DIMX, 1, 0, 0, 0, rows, DIMX, FFX, 1.0f);
    }
  }

  // ---- final LN + head ----
  ln_kernel<<<cdiv(BGX, 4), 256, 0, stream>>>(A3, lng, lnb, A0, BGX);
  head_kernel<<<cdiv(BGX, 4), 256, 0, stream>>>(A0, headw, headb, out);
}